// Round 5
// baseline (1011.975 us; speedup 1.0000x reference)
//
#include <hip/hip_runtime.h>
#include <cstdint>
#include <cstddef>

#define NTOT 6144
#define NDRUG 3072
#define NM (NTOT*64)
#define NBLK 768

typedef __fp16 f16;
typedef __attribute__((ext_vector_type(4))) __fp16 f16x4;
typedef __attribute__((ext_vector_type(8))) __fp16 f16x8;
typedef __attribute__((ext_vector_type(4))) float f32x4;

struct KParams {
  const float *graph, *drug_f, *dis_f;
  const int   *ts;
  const float *drug_w, *dis_w, *emb_w, *emb_b, *in_w, *in_b, *out_w, *out_b;
  const float *wq, *bq, *wk, *bkp, *wvw, *bv, *wo, *bo, *fuse_w, *fuse_b, *ln_g, *ln_b;
  float *norm; f16 *gh; f16 *nfst;
  float *target; f16 *qh; f16 *kh; f16 *vt;
  float *part; float *pattn; float *out;
  unsigned *bar;   // 4 one-shot barrier counters, zeroed before launch
};

// Device-scope grid barrier: one-shot counter per sync point.
// Requires all NBLK blocks co-resident (LDS 36.9KB -> 4/CU cap;
// __launch_bounds__(256,3) -> >=3 blocks/CU -> 768 resident on 256 CUs).
__device__ __forceinline__ void gridbar(unsigned* c){
  __syncthreads();                 // drains each wave's outstanding stores
  if (threadIdx.x == 0){
    __threadfence();               // release (agent scope: L2 writeback)
    __hip_atomic_fetch_add(c, 1u, __ATOMIC_ACQ_REL, __HIP_MEMORY_SCOPE_AGENT);
    while (__hip_atomic_load(c, __ATOMIC_ACQUIRE, __HIP_MEMORY_SCOPE_AGENT) < NBLK)
      __builtin_amdgcn_s_sleep(16);
    __threadfence();               // acquire (invalidate caches)
  }
  __syncthreads();
}

// Single fused kernel: 5 phases separated by software grid barriers.
// grid = 768 blocks x 256 threads, 3 blocks/CU co-resident.
// Phases 1/3/5 iterate 2 "virtual blocks" (2*768 = 1536 row-groups of 4).
// Phases 2/4 map bx -> (x = bx%96 tile-row, z = bx/96 k-slice).
__global__ __launch_bounds__(256, 3) void k_all(KParams P){
  __shared__ __align__(16) char smem[36864];
  const int tid = threadIdx.x;
  const int wv = tid >> 6, j = tid & 63;
  const int bx = blockIdx.x;

  // ---------------- Phase 1: rowsum->norm, fp16 graph copy, nfs^T ----------
  {
    float (*sx)[64]  = (float(*)[64])smem;
    float (*snf)[64] = (float(*)[64])(smem + 1024);
    for (int half = 0; half < 2; ++half){
      const int bi = bx*2 + half;
      const int row = bi*4 + wv;
      const float4* p = (const float4*)(P.graph + (size_t)row * NTOT);
      f16* ghrow = P.gh + (size_t)row * NTOT;
      float s = 0.f;
      #pragma unroll
      for (int it = 0; it < 24; ++it) {
        float4 u = p[it*64 + j];
        s += (u.x + u.y) + (u.z + u.w);
        f16x4 pk = {(f16)u.x, (f16)u.y, (f16)u.z, (f16)u.w};
        *(f16x4*)(ghrow + (size_t)(it*64 + j)*4) = pk;
      }
      #pragma unroll
      for (int off = 32; off; off >>= 1) s += __shfl_xor(s, off, 64);
      float nrm = rsqrtf(fmaxf(s, 1.0f));
      if (j == 0) P.norm[row] = nrm;

      const float* x; const float* W;
      if (row < NDRUG){ x = P.drug_f + (size_t)row*64; W = P.drug_w; }
      else            { x = P.dis_f + (size_t)(row-NDRUG)*64; W = P.dis_w; }
      sx[wv][j] = x[j];
      __syncthreads();
      float acc = 0.f;
      #pragma unroll 8
      for (int k = 0; k < 64; ++k) acc = fmaf(sx[wv][k], W[k*64+j], acc);
      snf[wv][j] = acc * nrm;
      __syncthreads();
      if (tid < 64){
        int c = tid;
        f16x4 pk = {(f16)snf[0][c], (f16)snf[1][c], (f16)snf[2][c], (f16)snf[3][c]};
        *(f16x4*)(P.nfst + (size_t)c*NTOT + bi*4) = pk;
      }
      __syncthreads();
    }
  }
  gridbar(P.bar + 0);

  // ---------------- Phase 2: split-K MFMA GEMM part[z] = A_tile @ nfs ------
  {
    typedef f16 (*TileP)[64][72];
    TileP sA = (TileP)smem;               // 2*64*72*2 = 18432 B
    TileP sB = (TileP)(smem + 18432);
    const int lane = tid & 63, w = tid >> 6;
    const int l15 = lane & 15, quad = lane >> 4;
    const int xb = bx % 96, z = bx / 96;
    const int row0 = xb * 64;
    const int kbase = z * 768;
    const int sr = tid >> 2, scg = (tid & 3) * 16;

    f32x4 acc[4] = {{0.f,0.f,0.f,0.f},{0.f,0.f,0.f,0.f},
                    {0.f,0.f,0.f,0.f},{0.f,0.f,0.f,0.f}};
    f16x8 ra0, ra1, rb0, rb1;
    auto LOADT = [&](int kt){
      const f16* pa = P.gh + (size_t)(row0 + sr)*NTOT + kbase + kt*64 + scg;
      ra0 = *(const f16x8*)pa; ra1 = *(const f16x8*)(pa + 8);
      const f16* pb = P.nfst + (size_t)sr*NTOT + kbase + kt*64 + scg;
      rb0 = *(const f16x8*)pb; rb1 = *(const f16x8*)(pb + 8);
    };
    auto WRITET = [&](int b){
      *(f16x8*)&sA[b][sr][scg]     = ra0;
      *(f16x8*)&sA[b][sr][scg + 8] = ra1;
      *(f16x8*)&sB[b][sr][scg]     = rb0;
      *(f16x8*)&sB[b][sr][scg + 8] = rb1;
    };
    LOADT(0); WRITET(0);
    int cur = 0;
    for (int kt = 0; kt < 12; ++kt){
      if (kt < 11) LOADT(kt + 1);
      __syncthreads();
      #pragma unroll
      for (int k16 = 0; k16 < 4; ++k16){
        f16x4 af = *(const f16x4*)&sA[cur][w*16 + l15][k16*16 + quad*4];
        #pragma unroll
        for (int nt = 0; nt < 4; ++nt){
          f16x4 bf = *(const f16x4*)&sB[cur][nt*16 + l15][k16*16 + quad*4];
          acc[nt] = __builtin_amdgcn_mfma_f32_16x16x16f16(af, bf, acc[nt], 0, 0, 0);
        }
      }
      if (kt < 11) WRITET(cur ^ 1);
      cur ^= 1;
      if (kt < 11) __syncthreads();
    }
    float* dst = P.part + (size_t)z * NM;
    #pragma unroll
    for (int nt = 0; nt < 4; ++nt){
      #pragma unroll
      for (int r = 0; r < 4; ++r){
        int row = row0 + w*16 + quad*4 + r;
        dst[(size_t)row*64 + nt*16 + l15] = acc[nt][r];
      }
    }
  }
  gridbar(P.bar + 1);

  // ---------------- Phase 3: finish + time-emb MLP + qkv -------------------
  {
    float (*sx)[80]  = (float(*)[80])smem;            // 1280 B
    float (*sh)[256] = (float(*)[256])(smem + 1280);  // 4096 B
    float (*sa)[64]  = (float(*)[64])(smem + 5376);   // 1024 B
    float (*sv)[64]  = (float(*)[64])(smem + 6400);   // 1024 B
    for (int half = 0; half < 2; ++half){
      const int bi = bx*2 + half;
      const int row = bi*4 + wv;
      float t = 0.f;
      #pragma unroll
      for (int p = 0; p < 8; ++p) t += P.part[(size_t)p*NM + (size_t)row*64 + j];
      t *= P.norm[row];
      P.target[(size_t)row*64 + j] = t;
      sx[wv][j] = t;
      if (j < 16) {
        const float FREQ[8] = {1.0f, 0.316227766016838f, 0.1f, 0.0316227766016838f,
                               0.01f, 0.00316227766016838f, 0.001f, 0.000316227766016838f};
        float tt = (float)P.ts[row];
        float e = P.emb_b[j];
        #pragma unroll
        for (int k = 0; k < 8; ++k) {
          float a = tt * FREQ[k];
          e = fmaf(cosf(a), P.emb_w[k*16 + j], e);
          e = fmaf(sinf(a), P.emb_w[(8+k)*16 + j], e);
        }
        sx[wv][64 + j] = e;
      }
      __syncthreads();
      float a0 = P.in_b[4*j+0], a1 = P.in_b[4*j+1], a2 = P.in_b[4*j+2], a3 = P.in_b[4*j+3];
      #pragma unroll 8
      for (int k = 0; k < 80; ++k) {
        float xv = sx[wv][k];
        float4 w = *(const float4*)(P.in_w + k*256 + 4*j);
        a0 = fmaf(xv, w.x, a0);
        a1 = fmaf(xv, w.y, a1);
        a2 = fmaf(xv, w.z, a2);
        a3 = fmaf(xv, w.w, a3);
      }
      sh[wv][4*j+0] = tanhf(a0); sh[wv][4*j+1] = tanhf(a1);
      sh[wv][4*j+2] = tanhf(a2); sh[wv][4*j+3] = tanhf(a3);
      __syncthreads();
      float o = P.out_b[j];
      #pragma unroll 8
      for (int k = 0; k < 256; ++k) o = fmaf(sh[wv][k], P.out_w[k*64 + j], o);
      sa[wv][j] = o;
      __syncthreads();
      float q = P.bq[j], kk = P.bkp[j], vvv = P.bv[j];
      #pragma unroll 8
      for (int k = 0; k < 64; ++k) {
        float tv = sx[wv][k], av = sa[wv][k];
        q   = fmaf(tv, P.wq[k*64+j],  q);
        kk  = fmaf(av, P.wk[k*64+j],  kk);
        vvv = fmaf(av, P.wvw[k*64+j], vvv);
      }
      // q pre-scaled by 1/sqrt(hd)=0.25 (exact pow2, commutes with fp16 rounding)
      P.qh[(size_t)row*64+j] = (f16)(q * 0.25f);
      P.kh[(size_t)row*64+j] = (f16)kk;
      sv[wv][j] = vvv;
      __syncthreads();
      if (tid < 64){
        int c = tid;
        f16x4 pk = {(f16)sv[0][c], (f16)sv[1][c], (f16)sv[2][c], (f16)sv[3][c]};
        *(f16x4*)(P.vt + (size_t)c*NTOT + bi*4) = pk;
      }
      __syncthreads();
    }
  }
  gridbar(P.bar + 2);

  // ---------------- Phase 4: MFMA flash attention per-slice partials -------
  {
    typedef f16 (*TileP)[64][72];
    TileP sK = (TileP)smem;
    TileP sV = (TileP)(smem + 18432);
    const int h = tid >> 6;
    const int lane = tid & 63;
    const int l15 = lane & 15, quad = lane >> 4;
    const int z = bx / 96;
    const int q0 = (bx % 96) * 64;

    f16x4 qf[4];
    #pragma unroll
    for (int qn = 0; qn < 4; ++qn)
      qf[qn] = *(const f16x4*)(P.qh + (size_t)(q0 + qn*16 + l15)*64 + h*16 + quad*4);

    f32x4 accOT[4] = {{0.f,0.f,0.f,0.f},{0.f,0.f,0.f,0.f},
                      {0.f,0.f,0.f,0.f},{0.f,0.f,0.f,0.f}};
    float lsum[4] = {0.f, 0.f, 0.f, 0.f};
    const int sr = tid >> 2, scg = (tid & 3) * 16;
    const int kbase = z * 768;
    f16x8 rk0, rk1, rv0, rv1;
    auto LOADT = [&](int kt){
      const int k0 = kbase + kt*64;
      const f16* pk = P.kh + (size_t)(k0 + sr)*64 + scg;
      rk0 = *(const f16x8*)pk; rk1 = *(const f16x8*)(pk + 8);
      const f16* pv = P.vt + (size_t)sr*NTOT + k0 + scg;
      rv0 = *(const f16x8*)pv; rv1 = *(const f16x8*)(pv + 8);
    };
    auto WRITET = [&](int b){
      *(f16x8*)&sK[b][sr][scg]     = rk0;
      *(f16x8*)&sK[b][sr][scg + 8] = rk1;
      *(f16x8*)&sV[b][sr][scg]     = rv0;
      *(f16x8*)&sV[b][sr][scg + 8] = rv1;
    };
    LOADT(0); WRITET(0);
    int cur = 0;
    for (int kt = 0; kt < 12; ++kt){
      if (kt < 11) LOADT(kt + 1);
      __syncthreads();
      #pragma unroll
      for (int km = 0; km < 4; ++km){
        f16x4 kf = *(const f16x4*)&sK[cur][km*16 + l15][h*16 + quad*4];
        f16x4 vf = *(const f16x4*)&sV[cur][h*16 + l15][km*16 + quad*4];
        #pragma unroll
        for (int qn = 0; qn < 4; ++qn){
          f32x4 s = __builtin_amdgcn_mfma_f32_16x16x16f16(
              kf, qf[qn], (f32x4){0.f,0.f,0.f,0.f}, 0, 0, 0);
          float p0 = __expf(fminf(s[0], 10.f));
          float p1 = __expf(fminf(s[1], 10.f));
          float p2 = __expf(fminf(s[2], 10.f));
          float p3 = __expf(fminf(s[3], 10.f));
          lsum[qn] += (p0 + p1) + (p2 + p3);
          f16x4 pf;
          pf[0] = (f16)p0; pf[1] = (f16)p1; pf[2] = (f16)p2; pf[3] = (f16)p3;
          accOT[qn] = __builtin_amdgcn_mfma_f32_16x16x16f16(vf, pf, accOT[qn], 0, 0, 0);
        }
      }
      if (kt < 11) WRITET(cur ^ 1);
      cur ^= 1;
      if (kt < 11) __syncthreads();
    }
    #pragma unroll
    for (int qn = 0; qn < 4; ++qn){
      lsum[qn] += __shfl_xor(lsum[qn], 16, 64);
      lsum[qn] += __shfl_xor(lsum[qn], 32, 64);
    }
    #pragma unroll
    for (int qn = 0; qn < 4; ++qn){
      float* rec = P.pattn + ((size_t)(z*4 + h)*NTOT + q0 + qn*16 + l15) * 20;
      *(float4*)(rec + quad*4) =
          make_float4(accOT[qn][0], accOT[qn][1], accOT[qn][2], accOT[qn][3]);
      if (quad == 0){ rec[17] = lsum[qn]; }
    }
  }
  gridbar(P.bar + 3);

  // ---------------- Phase 5: combine + out-proj + fuse + residual LN -------
  {
    float (*st)[64]  = (float(*)[64])smem;
    float (*sa)[64]  = (float(*)[64])(smem + 1024);
    float (*sao)[64] = (float(*)[64])(smem + 2048);
    const int h = j >> 4, d = j & 15;
    for (int half = 0; half < 2; ++half){
      const int bi = bx*2 + half;
      const int row = bi*4 + wv;
      float osum = 0.f, L = 0.f;
      #pragma unroll
      for (int z = 0; z < 8; ++z) {
        const float* rec = P.pattn + ((size_t)(z*4 + h)*NTOT + row)*20;
        osum += rec[d];
        L += rec[17];
      }
      sa[wv][j] = osum / L;
      st[wv][j] = P.target[(size_t)row*64+j];
      __syncthreads();
      float ao = P.bo[j];
      #pragma unroll 8
      for (int k = 0; k < 64; ++k) ao = fmaf(sa[wv][k], P.wo[k*64+j], ao);
      sao[wv][j] = ao;
      __syncthreads();
      float f = P.fuse_b[j];
      #pragma unroll 8
      for (int k = 0; k < 64; ++k) f = fmaf(st[wv][k], P.fuse_w[k*64+j], f);
      #pragma unroll 8
      for (int k = 0; k < 64; ++k) f = fmaf(sao[wv][k], P.fuse_w[(64+k)*64+j], f);
      float x = f + st[wv][j];
      float s1 = x, s2 = x*x;
      #pragma unroll
      for (int off = 32; off; off >>= 1) { s1 += __shfl_xor(s1, off, 64); s2 += __shfl_xor(s2, off, 64); }
      float mu = s1*(1.f/64.f);
      float var = s2*(1.f/64.f) - mu*mu;
      float y = (x-mu)*rsqrtf(var + 1e-5f)*P.ln_g[j] + P.ln_b[j];
      P.out[(size_t)row*64 + j] = y;
      __syncthreads();
    }
  }
}

extern "C" void kernel_launch(void* const* d_in, const int* in_sizes, int n_in,
                              void* d_out, int out_size, void* d_ws, size_t ws_size,
                              hipStream_t stream) {
  KParams P;
  P.graph  = (const float*)d_in[0];
  P.drug_f = (const float*)d_in[1];
  P.dis_f  = (const float*)d_in[2];
  P.ts     = (const int*)d_in[3];
  P.drug_w = (const float*)d_in[4];
  P.dis_w  = (const float*)d_in[5];
  P.emb_w  = (const float*)d_in[6];
  P.emb_b  = (const float*)d_in[7];
  P.in_w   = (const float*)d_in[8];
  P.in_b   = (const float*)d_in[9];
  P.out_w  = (const float*)d_in[10];
  P.out_b  = (const float*)d_in[11];
  P.wq     = (const float*)d_in[12];
  P.bq     = (const float*)d_in[13];
  P.wk     = (const float*)d_in[14];
  P.bkp    = (const float*)d_in[15];
  P.wvw    = (const float*)d_in[16];
  P.bv     = (const float*)d_in[17];
  P.wo     = (const float*)d_in[18];
  P.bo     = (const float*)d_in[19];
  P.fuse_w = (const float*)d_in[20];
  P.fuse_b = (const float*)d_in[21];
  P.ln_g   = (const float*)d_in[22];
  P.ln_b   = (const float*)d_in[23];

  float* ws = (float*)d_ws;
  P.norm   = ws;                                     // floats [0..6143]
  P.bar    = (unsigned*)(ws + 6656);                 // 16 uints inside norm pad
  P.gh     = (f16*)(ws + 8192);                      // NTOT*NTOT halves
  float* base = ws + 8192 + (size_t)NTOT*NTOT/2;
  P.nfst   = (f16*)base;                             // 64*NTOT halves
  P.target = base + (size_t)64*NTOT/2;               // NM floats
  P.qh     = (f16*)(P.target + NM);                  // NM halves
  P.kh     = (f16*)(P.target + NM + NM/2);           // NM halves
  P.vt     = (f16*)(P.target + NM + NM);             // NM halves
  P.part   = P.target + NM + NM + NM/2;              // 8*NM floats
  P.pattn  = P.part + (size_t)8*NM;                  // 8*4*6144*20 floats
  P.out    = (float*)d_out;

  hipMemsetAsync((void*)P.bar, 0, 64, stream);       // zero barrier counters
  k_all<<<dim3(NBLK), dim3(256), 0, stream>>>(P);
}

// Round 6
// 400.708 us; speedup vs baseline: 2.5255x; 2.5255x over previous
//
#include <hip/hip_runtime.h>
#include <cstdint>
#include <cstddef>

#define NTOT 6144
#define NDRUG 3072
#define NM (NTOT*64)

typedef __fp16 f16;
typedef __attribute__((ext_vector_type(2))) __fp16 f16x2;
typedef __attribute__((ext_vector_type(4))) __fp16 f16x4;
typedef __attribute__((ext_vector_type(8))) __fp16 f16x8;
typedef __attribute__((ext_vector_type(4))) float f32x4;

__device__ __forceinline__ f16x8 pack8(float4 a, float4 b){
  f16x2 p0 = __builtin_amdgcn_cvt_pkrtz(a.x, a.y);
  f16x2 p1 = __builtin_amdgcn_cvt_pkrtz(a.z, a.w);
  f16x2 p2 = __builtin_amdgcn_cvt_pkrtz(b.x, b.y);
  f16x2 p3 = __builtin_amdgcn_cvt_pkrtz(b.z, b.w);
  f16x4 lo = __builtin_shufflevector(p0, p1, 0, 1, 2, 3);
  f16x4 hi = __builtin_shufflevector(p2, p3, 0, 1, 2, 3);
  return __builtin_shufflevector(lo, hi, 0, 1, 2, 3, 4, 5, 6, 7);
}

// ------- Kernel 1: rowsum -> norm; nfs^T fp16 (no graph copy) ---------------
__global__ __launch_bounds__(256) void k_deg(const float* __restrict__ g,
                                             const float* __restrict__ drug_f,
                                             const float* __restrict__ dis_f,
                                             const float* __restrict__ drug_w,
                                             const float* __restrict__ dis_w,
                                             float* __restrict__ norm,
                                             f16* __restrict__ nfst){
  __shared__ float sx[4][64];
  __shared__ float snf[4][64];
  int wv = threadIdx.x >> 6, j = threadIdx.x & 63;
  int row = blockIdx.x*4 + wv;
  const float4* p = (const float4*)(g + (size_t)row * NTOT);
  float s = 0.f;
  #pragma unroll
  for (int it = 0; it < 24; ++it) {
    float4 u = p[it*64 + j];
    s += (u.x + u.y) + (u.z + u.w);
  }
  #pragma unroll
  for (int off = 32; off; off >>= 1) s += __shfl_xor(s, off, 64);
  float nrm = rsqrtf(fmaxf(s, 1.0f));
  if (j == 0) norm[row] = nrm;

  const float* x; const float* W;
  if (row < NDRUG){ x = drug_f + (size_t)row*64; W = drug_w; }
  else            { x = dis_f + (size_t)(row-NDRUG)*64; W = dis_w; }
  sx[wv][j] = x[j];
  __syncthreads();
  float acc = 0.f;
  #pragma unroll 8
  for (int k = 0; k < 64; ++k) acc = fmaf(sx[wv][k], W[k*64+j], acc);
  snf[wv][j] = acc * nrm;
  __syncthreads();
  if (threadIdx.x < 64){
    int c = threadIdx.x;
    f16x4 pk = {(f16)snf[0][c], (f16)snf[1][c], (f16)snf[2][c], (f16)snf[3][c]};
    *(f16x4*)(nfst + (size_t)c*NTOT + blockIdx.x*4) = pk;
  }
}

// ---------------- Kernel 2: MFMA split-K GEMM: part[z] = graph_tile @ nfs ---
// grid (96, 8), block 256 = 4 waves. A read fp32 + packed to fp16 in staging
// (hidden under MFMA by the register-staged double buffer, 1 barrier/kt).
__global__ __launch_bounds__(256) void k_gemm(const float* __restrict__ graph,
                                              const f16* __restrict__ nfst,
                                              float* __restrict__ part){
  __shared__ f16 sA[2][64][72];
  __shared__ f16 sB[2][64][72];
  const int tid = threadIdx.x;
  const int lane = tid & 63, w = tid >> 6;
  const int l15 = lane & 15, quad = lane >> 4;
  const int row0 = blockIdx.x * 64;
  const int kbase = blockIdx.y * 768;
  const int sr = tid >> 2, scg = (tid & 3) * 16;

  f32x4 acc[4] = {{0.f,0.f,0.f,0.f},{0.f,0.f,0.f,0.f},
                  {0.f,0.f,0.f,0.f},{0.f,0.f,0.f,0.f}};
  float4 a0, a1, a2, a3;
  f16x8 rb0, rb1;
  auto LOADT = [&](int kt){
    const float4* pa = (const float4*)(graph + (size_t)(row0 + sr)*NTOT + kbase + kt*64 + scg);
    a0 = pa[0]; a1 = pa[1]; a2 = pa[2]; a3 = pa[3];
    const f16* pb = nfst + (size_t)sr*NTOT + kbase + kt*64 + scg;
    rb0 = *(const f16x8*)pb; rb1 = *(const f16x8*)(pb + 8);
  };
  auto WRITET = [&](int b){
    *(f16x8*)&sA[b][sr][scg]     = pack8(a0, a1);
    *(f16x8*)&sA[b][sr][scg + 8] = pack8(a2, a3);
    *(f16x8*)&sB[b][sr][scg]     = rb0;
    *(f16x8*)&sB[b][sr][scg + 8] = rb1;
  };
  LOADT(0); WRITET(0);
  int cur = 0;
  for (int kt = 0; kt < 12; ++kt){
    if (kt < 11) LOADT(kt + 1);
    __syncthreads();
    #pragma unroll
    for (int k16 = 0; k16 < 4; ++k16){
      f16x4 af = *(const f16x4*)&sA[cur][w*16 + l15][k16*16 + quad*4];
      #pragma unroll
      for (int nt = 0; nt < 4; ++nt){
        f16x4 bf = *(const f16x4*)&sB[cur][nt*16 + l15][k16*16 + quad*4];
        acc[nt] = __builtin_amdgcn_mfma_f32_16x16x16f16(af, bf, acc[nt], 0, 0, 0);
      }
    }
    if (kt < 11) WRITET(cur ^ 1);
    cur ^= 1;
  }
  float* dst = part + (size_t)blockIdx.y * NM;
  #pragma unroll
  for (int nt = 0; nt < 4; ++nt){
    #pragma unroll
    for (int r = 0; r < 4; ++r){
      int row = row0 + w*16 + quad*4 + r;
      dst[(size_t)row*64 + nt*16 + l15] = acc[nt][r];
    }
  }
}

// ------- Kernel 3: finish + time-emb MLP + qkv (fused) -----------------------
// q pre-scaled by 0.25*log2(e) so attention can use native exp2.
__global__ __launch_bounds__(256) void k_node2(const float* __restrict__ part,
                                               const float* __restrict__ norm,
                                               const int* __restrict__ ts,
                                               const float* __restrict__ emb_w,
                                               const float* __restrict__ emb_b,
                                               const float* __restrict__ in_w,
                                               const float* __restrict__ in_b,
                                               const float* __restrict__ out_w,
                                               const float* __restrict__ out_b,
                                               const float* __restrict__ wq, const float* __restrict__ bq,
                                               const float* __restrict__ wk, const float* __restrict__ bk,
                                               const float* __restrict__ wvw, const float* __restrict__ bv,
                                               float* __restrict__ target,
                                               f16* __restrict__ qh, f16* __restrict__ kh,
                                               f16* __restrict__ vt){
  __shared__ float sx[4][80];    // [0..63]=target row, [64..79]=time emb
  __shared__ float sh[4][256];
  __shared__ float sa[4][64];    // aux row (LDS only)
  __shared__ float sv[4][64];    // v row (for transpose)
  int wv = threadIdx.x>>6, j = threadIdx.x&63;
  int row = blockIdx.x*4 + wv;

  float t = 0.f;
  #pragma unroll
  for (int p = 0; p < 8; ++p) t += part[(size_t)p*NM + (size_t)row*64 + j];
  t *= norm[row];
  target[(size_t)row*64 + j] = t;
  sx[wv][j] = t;
  if (j < 16) {
    const float FREQ[8] = {1.0f, 0.316227766016838f, 0.1f, 0.0316227766016838f,
                           0.01f, 0.00316227766016838f, 0.001f, 0.000316227766016838f};
    float tt = (float)ts[row];
    float e = emb_b[j];
    #pragma unroll
    for (int k = 0; k < 8; ++k) {
      float a = tt * FREQ[k];
      e = fmaf(cosf(a), emb_w[k*16 + j], e);
      e = fmaf(sinf(a), emb_w[(8+k)*16 + j], e);
    }
    sx[wv][64 + j] = e;
  }
  __syncthreads();
  float a0 = in_b[4*j+0], a1 = in_b[4*j+1], a2 = in_b[4*j+2], a3 = in_b[4*j+3];
  #pragma unroll 8
  for (int k = 0; k < 80; ++k) {
    float xv = sx[wv][k];
    float4 w = *(const float4*)(in_w + k*256 + 4*j);
    a0 = fmaf(xv, w.x, a0);
    a1 = fmaf(xv, w.y, a1);
    a2 = fmaf(xv, w.z, a2);
    a3 = fmaf(xv, w.w, a3);
  }
  sh[wv][4*j+0] = tanhf(a0); sh[wv][4*j+1] = tanhf(a1);
  sh[wv][4*j+2] = tanhf(a2); sh[wv][4*j+3] = tanhf(a3);
  __syncthreads();
  float o = out_b[j];
  #pragma unroll 8
  for (int k = 0; k < 256; ++k) o = fmaf(sh[wv][k], out_w[k*64 + j], o);
  sa[wv][j] = o;
  __syncthreads();
  float q = bq[j], kk = bk[j], vv = bv[j];
  #pragma unroll 8
  for (int k = 0; k < 64; ++k) {
    float tv = sx[wv][k], av = sa[wv][k];
    q  = fmaf(tv, wq[k*64+j],  q);
    kk = fmaf(av, wk[k*64+j],  kk);
    vv = fmaf(av, wvw[k*64+j], vv);
  }
  // q scaled by (1/sqrt(hd)) * log2(e) so scores are in exp2 domain
  qh[(size_t)row*64+j] = (f16)(q * 0.360673760222241f);
  kh[(size_t)row*64+j] = (f16)kk;
  sv[wv][j] = vv;
  __syncthreads();
  if (threadIdx.x < 64){
    int c = threadIdx.x;
    f16x4 pk = {(f16)sv[0][c], (f16)sv[1][c], (f16)sv[2][c], (f16)sv[3][c]};
    *(f16x4*)(vt + (size_t)c*NTOT + blockIdx.x*4) = pk;
  }
}

// ---------------- Kernel 4: MFMA flash attention per-slice partials ----------
// grid (96 qblocks, 8 z-slices), block 256 = 4 waves; wave = head.
// exp2 domain (q pre-scaled); clamp at 10*log2(e) == old exp(min(.,10)).
// Outputs: Opart[z][row][64] (coalesced full-line) + Lpart[z][h][row].
__global__ __launch_bounds__(256) void k_attn(const f16* __restrict__ qh,
                                              const f16* __restrict__ kh,
                                              const f16* __restrict__ vt,
                                              float* __restrict__ opart,
                                              float* __restrict__ lpart){
  __shared__ f16 sK[2][64][72];   // [key][d]
  __shared__ f16 sV[2][64][72];   // [d][key]
  const int tid = threadIdx.x;
  const int h = tid >> 6;
  const int lane = tid & 63;
  const int l15 = lane & 15, quad = lane >> 4;
  const int z = blockIdx.y;
  const int q0 = blockIdx.x * 64;

  f16x4 qf[4];
  #pragma unroll
  for (int qn = 0; qn < 4; ++qn)
    qf[qn] = *(const f16x4*)(qh + (size_t)(q0 + qn*16 + l15)*64 + h*16 + quad*4);

  f32x4 accOT[4] = {{0.f,0.f,0.f,0.f},{0.f,0.f,0.f,0.f},
                    {0.f,0.f,0.f,0.f},{0.f,0.f,0.f,0.f}};
  float lsum[4] = {0.f, 0.f, 0.f, 0.f};
  const int sr = tid >> 2, scg = (tid & 3) * 16;
  const int kbase = z * 768;
  f16x8 rk0, rk1, rv0, rv1;
  auto LOADT = [&](int kt){
    const int k0 = kbase + kt*64;
    const f16* pk = kh + (size_t)(k0 + sr)*64 + scg;
    rk0 = *(const f16x8*)pk; rk1 = *(const f16x8*)(pk + 8);
    const f16* pv = vt + (size_t)sr*NTOT + k0 + scg;
    rv0 = *(const f16x8*)pv; rv1 = *(const f16x8*)(pv + 8);
  };
  auto WRITET = [&](int b){
    *(f16x8*)&sK[b][sr][scg]     = rk0;
    *(f16x8*)&sK[b][sr][scg + 8] = rk1;
    *(f16x8*)&sV[b][sr][scg]     = rv0;
    *(f16x8*)&sV[b][sr][scg + 8] = rv1;
  };
  LOADT(0); WRITET(0);
  int cur = 0;
  for (int kt = 0; kt < 12; ++kt){
    if (kt < 11) LOADT(kt + 1);
    __syncthreads();
    #pragma unroll
    for (int km = 0; km < 4; ++km){
      f16x4 kf = *(const f16x4*)&sK[cur][km*16 + l15][h*16 + quad*4];
      f16x4 vf = *(const f16x4*)&sV[cur][h*16 + l15][km*16 + quad*4];
      #pragma unroll
      for (int qn = 0; qn < 4; ++qn){
        f32x4 s = __builtin_amdgcn_mfma_f32_16x16x16f16(
            kf, qf[qn], (f32x4){0.f,0.f,0.f,0.f}, 0, 0, 0);
        float p0 = exp2f(fminf(s[0], 14.4269504088896f));
        float p1 = exp2f(fminf(s[1], 14.4269504088896f));
        float p2 = exp2f(fminf(s[2], 14.4269504088896f));
        float p3 = exp2f(fminf(s[3], 14.4269504088896f));
        lsum[qn] += (p0 + p1) + (p2 + p3);
        f16x2 plo = __builtin_amdgcn_cvt_pkrtz(p0, p1);
        f16x2 phi = __builtin_amdgcn_cvt_pkrtz(p2, p3);
        f16x4 pf = __builtin_shufflevector(plo, phi, 0, 1, 2, 3);
        accOT[qn] = __builtin_amdgcn_mfma_f32_16x16x16f16(vf, pf, accOT[qn], 0, 0, 0);
      }
    }
    if (kt < 11) WRITET(cur ^ 1);
    cur ^= 1;
  }
  #pragma unroll
  for (int qn = 0; qn < 4; ++qn){
    lsum[qn] += __shfl_xor(lsum[qn], 16, 64);
    lsum[qn] += __shfl_xor(lsum[qn], 32, 64);
  }
  #pragma unroll
  for (int qn = 0; qn < 4; ++qn){
    const int row = q0 + qn*16 + l15;
    *(float4*)(opart + (size_t)z*NM + (size_t)row*64 + h*16 + quad*4) =
        make_float4(accOT[qn][0], accOT[qn][1], accOT[qn][2], accOT[qn][3]);
    if (quad == 0) lpart[((size_t)z*4 + h)*NTOT + row] = lsum[qn];
  }
}

// ------- Kernel 5: combine slices + out-proj + fuse + residual LN (fused) ----
__global__ __launch_bounds__(256) void k_out(const float* __restrict__ opart,
                                             const float* __restrict__ lpart,
                                             const float* __restrict__ target,
                                             const float* __restrict__ wo, const float* __restrict__ bo,
                                             const float* __restrict__ fuse_w, const float* __restrict__ fuse_b,
                                             const float* __restrict__ ln_g, const float* __restrict__ ln_b,
                                             float* __restrict__ out){
  __shared__ float st[4][64], sa[4][64], sao[4][64];
  int wv = threadIdx.x>>6, j = threadIdx.x&63;
  int row = blockIdx.x*4 + wv;
  int h = j >> 4;
  float osum = 0.f, L = 0.f;
  #pragma unroll
  for (int z = 0; z < 8; ++z) {
    osum += opart[(size_t)z*NM + (size_t)row*64 + j];
    L    += lpart[((size_t)z*4 + h)*NTOT + row];
  }
  sa[wv][j] = osum / L;
  st[wv][j] = target[(size_t)row*64+j];
  __syncthreads();
  float ao = bo[j];
  #pragma unroll 8
  for (int k = 0; k < 64; ++k) ao = fmaf(sa[wv][k], wo[k*64+j], ao);
  sao[wv][j] = ao;
  __syncthreads();
  float f = fuse_b[j];
  #pragma unroll 8
  for (int k = 0; k < 64; ++k) f = fmaf(st[wv][k], fuse_w[k*64+j], f);
  #pragma unroll 8
  for (int k = 0; k < 64; ++k) f = fmaf(sao[wv][k], fuse_w[(64+k)*64+j], f);
  float x = f + st[wv][j];
  float s1 = x, s2 = x*x;
  #pragma unroll
  for (int off = 32; off; off >>= 1) { s1 += __shfl_xor(s1, off, 64); s2 += __shfl_xor(s2, off, 64); }
  float mu = s1*(1.f/64.f);
  float var = s2*(1.f/64.f) - mu*mu;
  float y = (x-mu)*rsqrtf(var + 1e-5f)*ln_g[j] + ln_b[j];
  out[(size_t)row*64 + j] = y;
}

extern "C" void kernel_launch(void* const* d_in, const int* in_sizes, int n_in,
                              void* d_out, int out_size, void* d_ws, size_t ws_size,
                              hipStream_t stream) {
  const float* graph  = (const float*)d_in[0];
  const float* drug_f = (const float*)d_in[1];
  const float* dis_f  = (const float*)d_in[2];
  const int*   ts     = (const int*)d_in[3];
  const float* drug_w = (const float*)d_in[4];
  const float* dis_w  = (const float*)d_in[5];
  const float* emb_w  = (const float*)d_in[6];
  const float* emb_b  = (const float*)d_in[7];
  const float* in_w   = (const float*)d_in[8];
  const float* in_b   = (const float*)d_in[9];
  const float* out_w  = (const float*)d_in[10];
  const float* out_b  = (const float*)d_in[11];
  const float* wq     = (const float*)d_in[12];
  const float* bq     = (const float*)d_in[13];
  const float* wk     = (const float*)d_in[14];
  const float* bk     = (const float*)d_in[15];
  const float* wvw    = (const float*)d_in[16];
  const float* bv     = (const float*)d_in[17];
  const float* wo     = (const float*)d_in[18];
  const float* bo     = (const float*)d_in[19];
  const float* fuse_w = (const float*)d_in[20];
  const float* fuse_b = (const float*)d_in[21];
  const float* ln_g   = (const float*)d_in[22];
  const float* ln_b   = (const float*)d_in[23];

  float* ws     = (float*)d_ws;
  float* norm   = ws;                                  // 8192 floats (6144 used)
  f16*   nfst   = (f16*)(ws + 8192);                   // 64*NTOT halves
  float* target = ws + 8192 + (size_t)64*NTOT/2;       // NM floats
  f16*   qh     = (f16*)(target + NM);                 // NM halves
  f16*   kh     = (f16*)(target + NM + NM/2);          // NM halves
  f16*   vt     = (f16*)(target + NM + NM);            // NM halves
  float* part   = target + NM + NM + NM/2;             // 8*NM floats
  float* opart  = part + (size_t)8*NM;                 // 8*NM floats
  float* lpart  = opart + (size_t)8*NM;                // 8*4*NTOT floats

  k_deg<<<1536, 256, 0, stream>>>(graph, drug_f, dis_f, drug_w, dis_w, norm, nfst);
  k_gemm<<<dim3(96, 8), 256, 0, stream>>>(graph, nfst, part);
  k_node2<<<1536, 256, 0, stream>>>(part, norm, ts, emb_w, emb_b, in_w, in_b,
                                    out_w, out_b, wq, bq, wk, bk, wvw, bv,
                                    target, qh, kh, vt);
  k_attn<<<dim3(96, 8), 256, 0, stream>>>(qh, kh, vt, opart, lpart);
  k_out<<<1536, 256, 0, stream>>>(opart, lpart, target, wo, bo, fuse_w, fuse_b,
                                  ln_g, ln_b, (float*)d_out);
}